// Round 2
// baseline (1221.302 us; speedup 1.0000x reference)
//
#include <hip/hip_runtime.h>
#include <hip/hip_bf16.h>
#include <cstdint>

#define FEAT 2048
#define NH 32
#define DIN 2112          // FEAT + 2*H
#define NE 8
#define ED 32
#define HID 1024
#define VOCAB 50257
#define NPAD 50304        // 393 * 128

typedef __attribute__((ext_vector_type(8))) short short8;
typedef __attribute__((ext_vector_type(4))) float f32x4;

// ---------------------------------------------------------------------------
// Kernel A: per-row pipeline, 4 rows per block (wave w owns row w for the
// scalar stages; expert stage shares each We load across 4 rows).
// ---------------------------------------------------------------------------
__global__ __launch_bounds__(256) void rowpipe_kernel(
    const float* __restrict__ x, const float* __restrict__ Wg,
    const float* __restrict__ bg, const float* __restrict__ We,
    const float* __restrict__ be, const float* __restrict__ Wo,
    const float* __restrict__ bo, float* __restrict__ ctx)
{
  __shared__ __align__(16) float sEnh[4][DIN];
  __shared__ float sGate[4][NE];
  __shared__ float sMix[4][NE][ED];
  __shared__ float sMixed[4][ED];

  const int t = threadIdx.x;
  const int wv = t >> 6, ln = t & 63;
  const int b0 = blockIdx.x * 4;

  // --- 1. wave wv loads row wv into LDS + row mean (register broadcast) ---
  float s;
  {
    const float4* x4 = (const float4*)(x + (size_t)(b0 + wv) * FEAT);
    float4* e4 = (float4*)sEnh[wv];
    float ls = 0.f;
#pragma unroll
    for (int i = 0; i < 8; ++i) {
      float4 v = x4[ln + i * 64];
      e4[ln + i * 64] = v;
      ls += v.x + v.y + v.z + v.w;
    }
#pragma unroll
    for (int o = 32; o > 0; o >>= 1) ls += __shfl_xor(ls, o, 64);
    s = ls * (1.f / FEAT);      // all lanes hold the row mean
  }

  // --- 2. phasor features for own row (no cross-wave dep yet) ---
  {
    int k = (ln & 31) + 1;
    float ph = (43.98229715025711f * s) * (float)k;  // 2*pi*delta0
    sEnh[wv][FEAT + ln] = (ln < 32) ? cosf(ph) : sinf(ph);
  }

  // --- 3. gate logits + softmax, wave wv -> row wv (shuffle reductions) ---
  {
    int e = ln & 7, g = ln >> 3;
    float p = 0.f;
    for (int d = g; d < DIN; d += 8) p += sEnh[wv][d] * Wg[d * NE + e];
    p += __shfl_xor(p, 8, 64);
    p += __shfl_xor(p, 16, 64);
    p += __shfl_xor(p, 32, 64);
    float logit = p + bg[e];
    float m = logit;
    m = fmaxf(m, __shfl_xor(m, 1, 64));
    m = fmaxf(m, __shfl_xor(m, 2, 64));
    m = fmaxf(m, __shfl_xor(m, 4, 64));
    float ex = expf(logit - m);
    float sm = ex;
    sm += __shfl_xor(sm, 1, 64);
    sm += __shfl_xor(sm, 2, 64);
    sm += __shfl_xor(sm, 4, 64);
    if (ln < 8) sGate[wv][e] = ex / sm;
  }
  __syncthreads();

  // --- 4. expert dots: thread (e = t>>5, h = t&31), all 4 rows share loads ---
  {
    int e = t >> 5, h = t & 31;
    const float* Wep = We + (size_t)e * (DIN * ED) + h;
    float a0 = 0.f, a1 = 0.f, a2 = 0.f, a3 = 0.f;
    const float4* r0 = (const float4*)sEnh[0];
    const float4* r1 = (const float4*)sEnh[1];
    const float4* r2 = (const float4*)sEnh[2];
    const float4* r3 = (const float4*)sEnh[3];
#pragma unroll 4
    for (int d4 = 0; d4 < DIN / 4; ++d4) {
      const float* wp = Wep + (size_t)(d4 * 4) * ED;
      float w0 = wp[0], w1 = wp[ED], w2 = wp[2 * ED], w3 = wp[3 * ED];
      float4 e0 = r0[d4], e1 = r1[d4], e2 = r2[d4], e3 = r3[d4];
      a0 = fmaf(e0.x, w0, a0); a0 = fmaf(e0.y, w1, a0);
      a0 = fmaf(e0.z, w2, a0); a0 = fmaf(e0.w, w3, a0);
      a1 = fmaf(e1.x, w0, a1); a1 = fmaf(e1.y, w1, a1);
      a1 = fmaf(e1.z, w2, a1); a1 = fmaf(e1.w, w3, a1);
      a2 = fmaf(e2.x, w0, a2); a2 = fmaf(e2.y, w1, a2);
      a2 = fmaf(e2.z, w2, a2); a2 = fmaf(e2.w, w3, a2);
      a3 = fmaf(e3.x, w0, a3); a3 = fmaf(e3.y, w1, a3);
      a3 = fmaf(e3.z, w2, a3); a3 = fmaf(e3.w, w3, a3);
    }
    float bb = be[e * ED + h];
    sMix[0][e][h] = sGate[0][e] * (a0 + bb);
    sMix[1][e][h] = sGate[1][e] * (a1 + bb);
    sMix[2][e][h] = sGate[2][e] * (a2 + bb);
    sMix[3][e][h] = sGate[3][e] * (a3 + bb);
  }
  __syncthreads();

  // --- 5. mix over experts ---
  if (t < 128) {
    int r = t >> 5, h = t & 31;
    float m = 0.f;
#pragma unroll
    for (int e2 = 0; e2 < NE; ++e2) m += sMix[r][e2][h];
    sMixed[r][h] = m;
  }
  __syncthreads();

  // --- 6. ctx = tanh(mixed @ Wo + bo), Wo loads shared across 4 rows ---
#pragma unroll
  for (int jj = 0; jj < 4; ++jj) {
    int j = t + jj * 256;
    float base = bo[j];
    float a0 = base, a1 = base, a2 = base, a3 = base;
#pragma unroll
    for (int kk = 0; kk < ED; ++kk) {
      float w = Wo[kk * HID + j];
      a0 = fmaf(sMixed[0][kk], w, a0);
      a1 = fmaf(sMixed[1][kk], w, a1);
      a2 = fmaf(sMixed[2][kk], w, a2);
      a3 = fmaf(sMixed[3][kk], w, a3);
    }
    ctx[(size_t)(b0 + 0) * HID + j] = tanhf(a0);
    ctx[(size_t)(b0 + 1) * HID + j] = tanhf(a1);
    ctx[(size_t)(b0 + 2) * HID + j] = tanhf(a2);
    ctx[(size_t)(b0 + 3) * HID + j] = tanhf(a3);
  }
}

// ---------------------------------------------------------------------------
// Kernel B: top-20 + spiking gains, single 64-lane wave, shuffle butterflies.
// ---------------------------------------------------------------------------
__global__ __launch_bounds__(64) void select_spike_kernel(
    const float* __restrict__ ctx, float* __restrict__ gains)
{
  __shared__ int tok[20];
  __shared__ float sCnt[20];
  const int ln = threadIdx.x;

  float v[16];
#pragma unroll
  for (int q = 0; q < 16; ++q) v[q] = ctx[q * 64 + ln];

  for (int sel = 0; sel < 20; ++sel) {
    float bv = -3e38f; int bi = -1;
#pragma unroll
    for (int q = 0; q < 16; ++q) {
      int idx = q * 64 + ln;
      if (v[q] > bv || (v[q] == bv && idx > bi)) { bv = v[q]; bi = idx; }
    }
#pragma unroll
    for (int o = 1; o < 64; o <<= 1) {
      float ov = __shfl_xor(bv, o, 64);
      int   oi = __shfl_xor(bi, o, 64);
      if (ov > bv || (ov == bv && oi > bi)) { bv = ov; bi = oi; }
    }
    // all lanes agree on (bv, bi)
    if ((bi & 63) == ln) v[bi >> 6] = -3e38f;
    if (ln == 0) tok[19 - sel] = bi;
    __syncthreads();   // single wave: cheap; orders LDS tok writes
  }

  // LIF k-winner sim over the 20 unique tokens (others never reach theta)
  if (ln == 0) {
    float vv[20], cn[20];
    for (int j = 0; j < 20; ++j) { vv[j] = 0.f; cn[j] = 0.f; }
    for (int st = 0; st < 20; ++st) {
      for (int j = 0; j < 20; ++j) vv[j] *= 0.7f;   // DECAY
      vv[st] += 1.0f;
      bool picked[20];
      for (int j = 0; j < 20; ++j) picked[j] = false;
      for (int w = 0; w < 5; ++w) {                 // K_WINNERS
        int best = -1; float bvv = 0.f;
        for (int j = 0; j < 20; ++j) {
          if (picked[j]) continue;
          if (vv[j] > bvv ||
              (best >= 0 && vv[j] == bvv && vv[j] > 0.f && tok[j] < tok[best])) {
            best = j; bvv = vv[j];
          }
        }
        if (best < 0 || bvv <= 0.f) break;
        picked[best] = true;
        if (bvv >= 1.0f) { cn[best] += 1.f; vv[best] = 0.f; }  // THETA
      }
    }
    for (int j = 0; j < 20; ++j) sCnt[j] = cn[j];
  }
  __syncthreads();

  // every lane writes its 16 gain entries exactly once (no RMW hazards)
#pragma unroll
  for (int q = 0; q < 16; ++q) {
    int idx = q * 64 + ln;
    float g = 1.0f;
    for (int j = 0; j < 20; ++j) if (tok[j] == idx) g += sCnt[j];
    gains[idx] = g;
  }
}

// ---------------------------------------------------------------------------
// Kernel C: A_bf16[b][h] = bf16(ctx[b][h] * gains[h])
// ---------------------------------------------------------------------------
__global__ __launch_bounds__(256) void make_a_kernel(
    const float* __restrict__ ctx, const float* __restrict__ gains,
    __hip_bfloat16* __restrict__ A)
{
  const int b = blockIdx.x;
  const int h0 = threadIdx.x * 4;
  float4 cv = *(const float4*)&ctx[(size_t)b * HID + h0];
  float4 gv = *(const float4*)&gains[h0];
  union { __hip_bfloat16 h[4]; uint2 u; } p;
  p.h[0] = __float2bfloat16(cv.x * gv.x);
  p.h[1] = __float2bfloat16(cv.y * gv.y);
  p.h[2] = __float2bfloat16(cv.z * gv.z);
  p.h[3] = __float2bfloat16(cv.w * gv.w);
  *(uint2*)&A[(size_t)b * HID + h0] = p.u;
}

// ---------------------------------------------------------------------------
// Kernel D: transpose-convert Wout[1024][50257] f32 -> WT[50304][1024] bf16.
// 64x64 tiles: 256 B coalesced reads, 128 B coalesced bf16 writes.
// ---------------------------------------------------------------------------
__global__ __launch_bounds__(256) void wt_kernel(
    const float* __restrict__ Wout, __hip_bfloat16* __restrict__ WT)
{
  __shared__ float tile[64][65];
  const int n0 = blockIdx.x * 64;
  const int k0 = blockIdx.y * 64;
  const int lx = threadIdx.x & 63, wy = threadIdx.x >> 6;  // wy 0..3
#pragma unroll
  for (int i = 0; i < 16; ++i) {
    int kk = wy + i * 4;
    int n = n0 + lx;
    tile[kk][lx] = (n < VOCAB) ? Wout[(size_t)(k0 + kk) * VOCAB + n] : 0.f;
  }
  __syncthreads();
#pragma unroll
  for (int i = 0; i < 16; ++i) {
    int nn = wy + i * 4;
    WT[(size_t)(n0 + nn) * HID + k0 + lx] = __float2bfloat16(tile[lx][nn]);
  }
}

// ---------------------------------------------------------------------------
// Kernel E: C[2048][50257] = A[2048][1024] @ WT[50304][1024]^T + bout
// m97-style; grid: m-tile fastest-varying so all 16 m-blocks of one n-tile
// are dispatch-adjacent -> WT tile fetched from HBM once (L2/L3 reuse).
// ---------------------------------------------------------------------------
#define GL2LDS(g, l) __builtin_amdgcn_global_load_lds( \
    (const __attribute__((address_space(1))) void*)(g), \
    (__attribute__((address_space(3))) void*)(l), 16, 0, 0)

__global__ __launch_bounds__(256) void gemm_kernel(
    const __hip_bfloat16* __restrict__ A, const __hip_bfloat16* __restrict__ BT,
    const float* __restrict__ bout, float* __restrict__ C)
{
  __shared__ __align__(16) __hip_bfloat16 sA[128 * 32];
  __shared__ __align__(16) __hip_bfloat16 sB[128 * 32];

  const int t = threadIdx.x;
  const int lane = t & 63, wave = t >> 6;
  const int m0 = blockIdx.x * 128, n0 = blockIdx.y * 128;  // x = m (fast)
  const int wm = (wave & 1) * 64, wn = (wave >> 1) * 64;
  const int lr = lane & 15, quad = lane >> 4;

  f32x4 acc[4][4];
#pragma unroll
  for (int i = 0; i < 4; ++i)
#pragma unroll
    for (int j = 0; j < 4; ++j) acc[i][j] = (f32x4){0.f, 0.f, 0.f, 0.f};

  const int srow = wave * 16 + (lane >> 2);
  const int scol = (lane & 3) * 8;
  const __hip_bfloat16* agp0 = A  + (size_t)(m0 + srow) * HID + scol;
  const __hip_bfloat16* agp1 = agp0 + (size_t)64 * HID;
  const __hip_bfloat16* bgp0 = BT + (size_t)(n0 + srow) * HID + scol;
  const __hip_bfloat16* bgp1 = bgp0 + (size_t)64 * HID;
  __hip_bfloat16* al0 = sA + wave * 512;
  __hip_bfloat16* al1 = sA + 2048 + wave * 512;
  __hip_bfloat16* bl0 = sB + wave * 512;
  __hip_bfloat16* bl1 = sB + 2048 + wave * 512;

  for (int k0 = 0; k0 < HID; k0 += 32) {
    __syncthreads();
    GL2LDS(agp0 + k0, al0);
    GL2LDS(agp1 + k0, al1);
    GL2LDS(bgp0 + k0, bl0);
    GL2LDS(bgp1 + k0, bl1);
    __syncthreads();

    short8 af[4], bf[4];
#pragma unroll
    for (int i = 0; i < 4; ++i)
      af[i] = *(const short8*)&sA[(wm + i * 16 + lr) * 32 + quad * 8];
#pragma unroll
    for (int j = 0; j < 4; ++j)
      bf[j] = *(const short8*)&sB[(wn + j * 16 + lr) * 32 + quad * 8];
#pragma unroll
    for (int i = 0; i < 4; ++i)
#pragma unroll
      for (int j = 0; j < 4; ++j)
        acc[i][j] = __builtin_amdgcn_mfma_f32_16x16x32_bf16(af[i], bf[j], acc[i][j], 0, 0, 0);
  }

  // epilogue: C/D layout col = lane&15 (n), row = quad*4 + reg (m)
#pragma unroll
  for (int j = 0; j < 4; ++j) {
    int n = n0 + wn + j * 16 + lr;
    if (n >= VOCAB) continue;
    float bb = bout[n];
#pragma unroll
    for (int i = 0; i < 4; ++i) {
      int m = m0 + wm + i * 16 + quad * 4;
#pragma unroll
      for (int rr = 0; rr < 4; ++rr)
        C[(size_t)(m + rr) * VOCAB + n] = acc[i][j][rr] + bb;
    }
  }
}

// ---------------------------------------------------------------------------
extern "C" void kernel_launch(void* const* d_in, const int* in_sizes, int n_in,
                              void* d_out, int out_size, void* d_ws, size_t ws_size,
                              hipStream_t stream)
{
  const float* x    = (const float*)d_in[0];
  const float* Wg   = (const float*)d_in[1];
  const float* bg   = (const float*)d_in[2];
  const float* We   = (const float*)d_in[3];
  const float* be   = (const float*)d_in[4];
  const float* Wo   = (const float*)d_in[5];
  const float* bo   = (const float*)d_in[6];
  const float* Wout = (const float*)d_in[7];
  const float* bout = (const float*)d_in[8];
  float* out = (float*)d_out;

  char* ws = (char*)d_ws;
  float*          ctx   = (float*)ws;                          // 8 MB
  float*          gains = (float*)(ws + 8388608);              // 4 KB
  __hip_bfloat16* Abf   = (__hip_bfloat16*)(ws + 8392704);     // 4 MB
  __hip_bfloat16* WT    = (__hip_bfloat16*)(ws + 12587008);    // 103 MB

  rowpipe_kernel<<<512, 256, 0, stream>>>(x, Wg, bg, We, be, Wo, bo, ctx);
  select_spike_kernel<<<1, 64, 0, stream>>>(ctx, gains);
  make_a_kernel<<<2048, 256, 0, stream>>>(ctx, gains, Abf);
  wt_kernel<<<dim3(NPAD / 64, HID / 64), 256, 0, stream>>>(Wout, WT);
  gemm_kernel<<<dim3(16, NPAD / 128), 256, 0, stream>>>(Abf, WT, bout, out);
}